// Round 1
// baseline (1022.605 us; speedup 1.0000x reference)
//
#include <hip/hip_runtime.h>
#include <cstdint>
#include <cstddef>

#define DEVI __device__ __forceinline__

typedef __bf16 bf16x8 __attribute__((ext_vector_type(8)));
typedef float  floatx4 __attribute__((ext_vector_type(4)));

constexpr int NHEAD = 6;
constexpr int CLF = 64, CHF = 192;
constexpr int IMG = 256;
constexpr int HW  = IMG * IMG;

// LDS pitches (bf16 elements). Rows 16B-aligned (pitch % 8 == 0).
constexpr int PHF = 200;  // hf_n (64 x 192+8); aliased as O staging in epilogue
constexpr int PQK = 40;   // per-head Q,K (64 x 32+8)
constexpr int PVT = 72;   // V^T (32 x 64+8)
constexpr int PP  = 72;   // P / lf_n temp / per-head AO in cols 0..31 (64 x 64+8)

// LDS arena offsets (bytes), all 16B aligned
constexpr int OFF_HF  = 0;      // 64*200*2 = 25600 ; alias: O staging (epilogue)
constexpr int OFF_Q   = 25600;  // 64*40*2  = 5120  ; alias: s_red (4096B, load phase)
constexpr int OFF_K   = 30720;  // 5120
constexpr int OFF_VT  = 35840;  // 32*72*2  = 4608
constexpr int OFF_P   = 40448;  // 64*72*2  = 9216  ; alias: lf_n temp (load phase)
constexpr int OFF_RPB = 49664;  // 225*6*2  = 2700 -> 2704 (bf16 table)
constexpr int SMEM_BYTES = 52368;  // x3 blocks/CU = 157104 <= 163840

DEVI unsigned short f2b(float f) {  // fp32 -> bf16 RNE
  unsigned u = __float_as_uint(f);
  u += 0x7fffu + ((u >> 16) & 1u);
  return (unsigned short)(u >> 16);
}
DEVI float b2f(unsigned short s) { return __uint_as_float(((unsigned)s) << 16); }

DEVI floatx4 mfma_bf16(bf16x8 a, bf16x8 b, floatx4 c) {
  return __builtin_amdgcn_mfma_f32_16x16x32_bf16(a, b, c, 0, 0, 0);
}

// ---- prep: W[k][n] fp32 -> W^T[n][k] bf16 into workspace ----
__global__ void wca_prep(const float* __restrict__ Wq, const float* __restrict__ Wk,
                         const float* __restrict__ Wv, const float* __restrict__ Wo,
                         unsigned short* __restrict__ wT) {
  int i = blockIdx.x * 256 + threadIdx.x;  // grid covers exactly 122880
  if (i < 12288) {                         // WqT: 192 x 64
    int n = i >> 6, k = i & 63;
    wT[i] = f2b(Wq[k * 192 + n]);
  } else if (i < 49152) {                  // WkT: 192 x 192
    int j = i - 12288, n = j / 192, k = j - n * 192;
    wT[i] = f2b(Wk[k * 192 + n]);
  } else if (i < 86016) {                  // WvT
    int j = i - 49152, n = j / 192, k = j - n * 192;
    wT[i] = f2b(Wv[k * 192 + n]);
  } else {                                 // WoT
    int j = i - 86016, n = j / 192, k = j - n * 192;
    wT[i] = f2b(Wo[k * 192 + n]);
  }
}

__global__ __launch_bounds__(256, 3) void wca_main(
    const float* __restrict__ ylf, const float* __restrict__ yhf,
    const float* __restrict__ glf, const float* __restrict__ blf,
    const float* __restrict__ ghf, const float* __restrict__ bhf,
    const float* __restrict__ bq,  const float* __restrict__ bk,
    const float* __restrict__ bv,  const float* __restrict__ bo,
    const float* __restrict__ rpb, const unsigned short* __restrict__ wT,
    float* __restrict__ out) {
  __shared__ __align__(16) char smem[SMEM_BYTES];
  unsigned short* s_hf = (unsigned short*)(smem + OFF_HF);
  unsigned short* s_q  = (unsigned short*)(smem + OFF_Q);
  unsigned short* s_k  = (unsigned short*)(smem + OFF_K);
  unsigned short* s_vt = (unsigned short*)(smem + OFF_VT);
  unsigned short* s_p  = (unsigned short*)(smem + OFF_P);
  unsigned short* s_lf = s_p;               // lf_n temp, dead before first P write
  float* s_red = (float*)(smem + OFF_Q);    // load-phase only, dead before first Q write
  unsigned short* s_rpb = (unsigned short*)(smem + OFF_RPB);

  const int tid  = threadIdx.x;
  const int lane = tid & 63;
  const int wv   = tid >> 6;     // wave 0..3
  const int quad = lane >> 4;
  const int l16  = lane & 15;

  const int wid = blockIdx.x;          // 4096 windows
  const int b   = wid >> 10;
  const int wy  = (wid >> 5) & 31;
  const int wx  = wid & 31;
  const int h0  = wy << 3, w0 = wx << 3;

  const int t_own = tid & 63;          // token owned for load/stats (t = ty*8+tx)
  const int cg    = tid >> 6;          // channel block owner (wave-uniform)
  const int ty    = t_own >> 3, tx = t_own & 7;

  // stage RPB table as bf16 (|rpb| ~ 0.08 -> abs err <= 2e-4, negligible)
  for (int i = tid; i < 225 * NHEAD; i += 256) s_rpb[i] = f2b(rpb[i]);

  // ---- load windows (coalesced 32B row segments) + LN stats in fp32 ----
  // wave cg owns CONTIGUOUS channel blocks: lf [cg*16, +16), hf [cg*48, +48)
  float lfv[16], hfv[48];
  float ls = 0.f, l2 = 0.f, hs = 0.f, h2 = 0.f;
  {
    const float* p = ylf + ((size_t)(b * CLF + cg * 16) * IMG + (h0 + ty)) * IMG + (w0 + tx);
#pragma unroll
    for (int k = 0; k < 16; k++) {
      float v = p[(size_t)k * HW];
      lfv[k] = v; ls += v; l2 += v * v;
    }
  }
  {
    const float* p = yhf + ((size_t)(b * CHF + cg * 48) * IMG + (h0 + ty)) * IMG + (w0 + tx);
#pragma unroll
    for (int k = 0; k < 48; k++) {
      float v = p[(size_t)k * HW];
      hfv[k] = v; hs += v; h2 += v * v;
    }
  }
  s_red[0 * 256 + (cg << 6) + t_own] = ls;
  s_red[1 * 256 + (cg << 6) + t_own] = l2;
  s_red[2 * 256 + (cg << 6) + t_own] = hs;
  s_red[3 * 256 + (cg << 6) + t_own] = h2;
  __syncthreads();  // B1
  float su = 0.f, sq = 0.f, hu = 0.f, hq = 0.f;
#pragma unroll
  for (int g = 0; g < 4; g++) {
    su += s_red[0 * 256 + (g << 6) + t_own];
    sq += s_red[1 * 256 + (g << 6) + t_own];
    hu += s_red[2 * 256 + (g << 6) + t_own];
    hq += s_red[3 * 256 + (g << 6) + t_own];
  }
  const float mu_lf = su * (1.f / 64.f);
  const float rs_lf = rsqrtf(sq * (1.f / 64.f) - mu_lf * mu_lf + 1e-5f);
  const float mu_hf = hu * (1.f / 192.f);
  const float rs_hf = rsqrtf(hq * (1.f / 192.f) - mu_hf * mu_hf + 1e-5f);

  // normalize + packed u64 bf16 stores (4 channels/store: 8-way -> ~2-way bank conflicts)
#pragma unroll
  for (int j = 0; j < 4; j++) {
    uint64_t w = 0;
#pragma unroll
    for (int m = 0; m < 4; m++) {
      int c = cg * 16 + j * 4 + m;
      float v = (lfv[j * 4 + m] - mu_lf) * rs_lf * glf[c] + blf[c];
      w |= (uint64_t)f2b(v) << (16 * m);
    }
    *(uint64_t*)(s_lf + t_own * PP + cg * 16 + j * 4) = w;
  }
#pragma unroll
  for (int j = 0; j < 12; j++) {
    uint64_t w = 0;
#pragma unroll
    for (int m = 0; m < 4; m++) {
      int c = cg * 48 + j * 4 + m;
      float v = (hfv[j * 4 + m] - mu_hf) * rs_hf * ghf[c] + bhf[c];
      w |= (uint64_t)f2b(v) << (16 * m);
    }
    *(uint64_t*)(s_hf + t_own * PHF + cg * 48 + j * 4) = w;
  }
  __syncthreads();  // B2 (also: red-reads before first s_q write; lf-temp before first P write)

  // lf_n A-fragments for this wave's 16 query rows, kept in registers all heads
  bf16x8 alf0 = *(const bf16x8*)(s_lf + (wv * 16 + l16) * PP + quad * 8);
  bf16x8 alf1 = *(const bf16x8*)(s_lf + (wv * 16 + l16) * PP + 32 + quad * 8);

  const unsigned short* wqT = wT;           // [192][64]
  const unsigned short* wkT = wT + 12288;   // [192][192]
  const unsigned short* wvT = wT + 49152;
  const unsigned short* woT = wT + 86016;

  const int rowbase = wv * 16 + quad * 4;   // C-layout row base for this lane

  // O accumulators live across the whole head loop (48 VGPR)
  floatx4 oa[12];
  const floatx4 zero = {0.f, 0.f, 0.f, 0.f};
#pragma unroll
  for (int ct = 0; ct < 12; ct++) oa[ct] = zero;

  for (int h = 0; h < NHEAD; h++) {
    // ---- Q_h = lf_n @ Wq[:, h*32:+32] + bq ----
#pragma unroll
    for (int nt = 0; nt < 2; nt++) {
      const int n = h * 32 + nt * 16 + l16;
      floatx4 acc = {0.f, 0.f, 0.f, 0.f};
      acc = mfma_bf16(alf0, *(const bf16x8*)(wqT + n * 64 + quad * 8), acc);
      acc = mfma_bf16(alf1, *(const bf16x8*)(wqT + n * 64 + 32 + quad * 8), acc);
      const float bqv = bq[n];
#pragma unroll
      for (int r = 0; r < 4; r++)
        s_q[(rowbase + r) * PQK + nt * 16 + l16] = f2b(acc[r] + bqv);
    }
    // ---- K_h ----
#pragma unroll
    for (int nt = 0; nt < 2; nt++) {
      const int n = h * 32 + nt * 16 + l16;
      floatx4 acc = {0.f, 0.f, 0.f, 0.f};
#pragma unroll
      for (int ks = 0; ks < 6; ks++) {
        bf16x8 a  = *(const bf16x8*)(s_hf + (wv * 16 + l16) * PHF + ks * 32 + quad * 8);
        bf16x8 bb = *(const bf16x8*)(wkT + n * 192 + ks * 32 + quad * 8);
        acc = mfma_bf16(a, bb, acc);
      }
      const float bkv = bk[n];
#pragma unroll
      for (int r = 0; r < 4; r++)
        s_k[(rowbase + r) * PQK + nt * 16 + l16] = f2b(acc[r] + bkv);
    }
    // ---- V_h (stored transposed: vt[d][m] so PV B-frags are contiguous) ----
#pragma unroll
    for (int nt = 0; nt < 2; nt++) {
      const int n = h * 32 + nt * 16 + l16;
      floatx4 acc = {0.f, 0.f, 0.f, 0.f};
#pragma unroll
      for (int ks = 0; ks < 6; ks++) {
        bf16x8 a  = *(const bf16x8*)(s_hf + (wv * 16 + l16) * PHF + ks * 32 + quad * 8);
        bf16x8 bb = *(const bf16x8*)(wvT + n * 192 + ks * 32 + quad * 8);
        acc = mfma_bf16(a, bb, acc);
      }
      const float bvv = bv[n];
#pragma unroll
      for (int r = 0; r < 4; r++)
        s_vt[(nt * 16 + l16) * PVT + rowbase + r] = f2b(acc[r] + bvv);
    }
    __syncthreads();  // barrier A: K/V visible to all waves

    // ---- S = Q K^T * scale + rpb bias (wave w owns query rows w*16..+15) ----
    bf16x8 aq = *(const bf16x8*)(s_q + (wv * 16 + l16) * PQK + quad * 8);
    float sv[4][4];
#pragma unroll
    for (int ct = 0; ct < 4; ct++) {
      bf16x8 kb = *(const bf16x8*)(s_k + (ct * 16 + l16) * PQK + quad * 8);
      floatx4 acc = {0.f, 0.f, 0.f, 0.f};
      acc = mfma_bf16(aq, kb, acc);
#pragma unroll
      for (int r = 0; r < 4; r++) {
        int row = rowbase + r, col = ct * 16 + l16;
        int dy = (row >> 3) - (col >> 3) + 7;
        int dx = (row & 7) - (col & 7) + 7;
        sv[ct][r] = acc[r] * 0.17677669529663688f + b2f(s_rpb[(dy * 15 + dx) * NHEAD + h]);
      }
    }
    // ---- softmax over 64 keys: 4 in-lane + xor-shuffle over 16 lanes ----
#pragma unroll
    for (int r = 0; r < 4; r++) {
      float m = fmaxf(fmaxf(sv[0][r], sv[1][r]), fmaxf(sv[2][r], sv[3][r]));
      m = fmaxf(m, __shfl_xor(m, 1));
      m = fmaxf(m, __shfl_xor(m, 2));
      m = fmaxf(m, __shfl_xor(m, 4));
      m = fmaxf(m, __shfl_xor(m, 8));
      const float L2E = 1.4426950408889634f;
      float e0 = exp2f((sv[0][r] - m) * L2E);
      float e1 = exp2f((sv[1][r] - m) * L2E);
      float e2 = exp2f((sv[2][r] - m) * L2E);
      float e3 = exp2f((sv[3][r] - m) * L2E);
      float s = e0 + e1 + e2 + e3;
      s += __shfl_xor(s, 1);
      s += __shfl_xor(s, 2);
      s += __shfl_xor(s, 4);
      s += __shfl_xor(s, 8);
      float inv = 1.f / s;
      sv[0][r] = e0 * inv; sv[1][r] = e1 * inv; sv[2][r] = e2 * inv; sv[3][r] = e3 * inv;
    }
#pragma unroll
    for (int ct = 0; ct < 4; ct++)
#pragma unroll
      for (int r = 0; r < 4; r++)
        s_p[(rowbase + r) * PP + ct * 16 + l16] = f2b(sv[ct][r]);

    // ---- PV: own P rows (same-wave LDS round trip; no barrier needed) ----
    floatx4 pv0 = {0.f, 0.f, 0.f, 0.f}, pv1 = {0.f, 0.f, 0.f, 0.f};
#pragma unroll
    for (int ks = 0; ks < 2; ks++) {
      bf16x8 pa = *(const bf16x8*)(s_p + (wv * 16 + l16) * PP + ks * 32 + quad * 8);
      pv0 = mfma_bf16(pa, *(const bf16x8*)(s_vt + (0 * 16 + l16) * PVT + ks * 32 + quad * 8), pv0);
      pv1 = mfma_bf16(pa, *(const bf16x8*)(s_vt + (1 * 16 + l16) * PVT + ks * 32 + quad * 8), pv1);
    }
    // stage AO_h into s_p cols 0..31 (stores depend on pv -> cannot pass the pa reads;
    // same-wave DS ops retire in order, so the later reads see new data)
#pragma unroll
    for (int r = 0; r < 4; r++) {
      s_p[(rowbase + r) * PP + l16]      = f2b(pv0[r]);
      s_p[(rowbase + r) * PP + 16 + l16] = f2b(pv1[r]);
    }
    // ---- O += AO_h @ Wo[h*32:(h+1)*32, :]  (register accumulation, no s_ao buffer) ----
    bf16x8 aoh = *(const bf16x8*)(s_p + (wv * 16 + l16) * PP + quad * 8);
#pragma unroll
    for (int ct = 0; ct < 12; ct++) {
      bf16x8 bb = *(const bf16x8*)(woT + (ct * 16 + l16) * 192 + h * 32 + quad * 8);
      oa[ct] = mfma_bf16(aoh, bb, oa[ct]);
    }
    if (h < NHEAD - 1) __syncthreads();  // barrier B: before next head overwrites Q/K/V/P
    // (last head: epilogue writes only this wave's own rows of the dead s_hf region,
    //  and every wave's last s_hf read was before its own barrier A of head 5)
  }

  // ---- epilogue: stage O + bo (own rows) into dead s_hf region ----
  unsigned short* s_res = s_hf;
#pragma unroll
  for (int ct = 0; ct < 12; ct++) {
    const int col = ct * 16 + l16;
    const float bov = bo[col];
#pragma unroll
    for (int r = 0; r < 4; r++)
      s_res[(rowbase + r) * PHF + col] = f2b(oa[ct][r] + bov);
  }
  __syncthreads();  // final barrier before cross-row gather

  // ---- coalesced store: float4 per lane; residual added from coalesced global float4 ----
#pragma unroll
  for (int k = 0; k < 12; k++) {
    int chunk = k * 256 + tid;       // 3072 chunks of 4 floats = 192ch x 64tok
    int c   = chunk >> 4;
    int sub = chunk & 15;
    int yy  = sub >> 1;
    int x4  = (sub & 1) << 2;
    int t0  = (yy << 3) + x4;
    size_t gidx = ((size_t)(b * CHF + c) * IMG + (h0 + yy)) * IMG + w0 + x4;
    float4 res = *(const float4*)(yhf + gidx);
    float4 v;
    v.x = b2f(s_res[(t0 + 0) * PHF + c]) + res.x;
    v.y = b2f(s_res[(t0 + 1) * PHF + c]) + res.y;
    v.z = b2f(s_res[(t0 + 2) * PHF + c]) + res.z;
    v.w = b2f(s_res[(t0 + 3) * PHF + c]) + res.w;
    *(float4*)(out + gidx) = v;
  }
}

extern "C" void kernel_launch(void* const* d_in, const int* in_sizes, int n_in,
                              void* d_out, int out_size, void* d_ws, size_t ws_size,
                              hipStream_t stream) {
  const float* ylf = (const float*)d_in[0];
  const float* yhf = (const float*)d_in[1];
  const float* glf = (const float*)d_in[2];
  const float* blf = (const float*)d_in[3];
  const float* ghf = (const float*)d_in[4];
  const float* bhf = (const float*)d_in[5];
  const float* Wq  = (const float*)d_in[6];
  const float* bq  = (const float*)d_in[7];
  const float* Wk  = (const float*)d_in[8];
  const float* bk  = (const float*)d_in[9];
  const float* Wv  = (const float*)d_in[10];
  const float* bv  = (const float*)d_in[11];
  const float* Wo  = (const float*)d_in[12];
  const float* bo  = (const float*)d_in[13];
  const float* rpb = (const float*)d_in[14];
  unsigned short* wT = (unsigned short*)d_ws;  // 122880 bf16 = 245760 B

  wca_prep<<<480, 256, 0, stream>>>(Wq, Wk, Wv, Wo, wT);
  wca_main<<<4096, 256, 0, stream>>>(ylf, yhf, glf, blf, ghf, bhf,
                                     bq, bk, bv, bo, rpb, wT, (float*)d_out);
}

// Round 2
// 938.950 us; speedup vs baseline: 1.0891x; 1.0891x over previous
//
#include <hip/hip_runtime.h>
#include <cstdint>
#include <cstddef>

#define DEVI __device__ __forceinline__

typedef __bf16 bf16x8 __attribute__((ext_vector_type(8)));
typedef float  floatx4 __attribute__((ext_vector_type(4)));

constexpr int NHEAD = 6;
constexpr int CLF = 64, CHF = 192;
constexpr int IMG = 256;
constexpr int HW  = IMG * IMG;

// LDS pitches (bf16 elements). Rows 16B-aligned (pitch % 8 == 0).
constexpr int PHF = 200;  // hf_n (64 x 192+8); aliased as O staging in epilogue
constexpr int PQK = 40;   // per-head Q,K (64 x 32+8)
constexpr int PVT = 72;   // V^T (32 x 64+8)
constexpr int PP  = 72;   // P / lf_n temp / per-head AO in cols 0..31 (64 x 64+8)

// LDS arena offsets (bytes), all 16B aligned
constexpr int OFF_HF  = 0;      // 64*200*2 = 25600 ; alias: O staging (epilogue)
constexpr int OFF_Q   = 25600;  // 64*40*2  = 5120  ; alias: s_red (4096B, load phase)
constexpr int OFF_K   = 30720;  // 5120
constexpr int OFF_VT  = 35840;  // 32*72*2  = 4608
constexpr int OFF_P   = 40448;  // 64*72*2  = 9216  ; alias: lf_n temp (load phase)
constexpr int OFF_RPB = 49664;  // 225*6*2  = 2700 -> 2704 (bf16 table)
constexpr int SMEM_BYTES = 52368;  // x3 blocks/CU = 157104 <= 163840

DEVI unsigned short f2b(float f) {  // fp32 -> bf16 RNE
  unsigned u = __float_as_uint(f);
  u += 0x7fffu + ((u >> 16) & 1u);
  return (unsigned short)(u >> 16);
}
DEVI float b2f(unsigned short s) { return __uint_as_float(((unsigned)s) << 16); }

DEVI floatx4 mfma_bf16(bf16x8 a, bf16x8 b, floatx4 c) {
  return __builtin_amdgcn_mfma_f32_16x16x32_bf16(a, b, c, 0, 0, 0);
}

// ---- prep: W[k][n] fp32 -> W^T[n][k] bf16 into workspace ----
__global__ void wca_prep(const float* __restrict__ Wq, const float* __restrict__ Wk,
                         const float* __restrict__ Wv, const float* __restrict__ Wo,
                         unsigned short* __restrict__ wT) {
  int i = blockIdx.x * 256 + threadIdx.x;  // grid covers exactly 122880
  if (i < 12288) {                         // WqT: 192 x 64
    int n = i >> 6, k = i & 63;
    wT[i] = f2b(Wq[k * 192 + n]);
  } else if (i < 49152) {                  // WkT: 192 x 192
    int j = i - 12288, n = j / 192, k = j - n * 192;
    wT[i] = f2b(Wk[k * 192 + n]);
  } else if (i < 86016) {                  // WvT
    int j = i - 49152, n = j / 192, k = j - n * 192;
    wT[i] = f2b(Wv[k * 192 + n]);
  } else {                                 // WoT
    int j = i - 86016, n = j / 192, k = j - n * 192;
    wT[i] = f2b(Wo[k * 192 + n]);
  }
}

__global__ __launch_bounds__(256, 3) void wca_main(
    const float* __restrict__ ylf, const float* __restrict__ yhf,
    const float* __restrict__ glf, const float* __restrict__ blf,
    const float* __restrict__ ghf, const float* __restrict__ bhf,
    const float* __restrict__ bq,  const float* __restrict__ bk,
    const float* __restrict__ bv,  const float* __restrict__ bo,
    const float* __restrict__ rpb, const unsigned short* __restrict__ wT,
    float* __restrict__ out) {
  __shared__ __align__(16) char smem[SMEM_BYTES];
  unsigned short* s_hf = (unsigned short*)(smem + OFF_HF);
  unsigned short* s_q  = (unsigned short*)(smem + OFF_Q);
  unsigned short* s_k  = (unsigned short*)(smem + OFF_K);
  unsigned short* s_vt = (unsigned short*)(smem + OFF_VT);
  unsigned short* s_p  = (unsigned short*)(smem + OFF_P);
  unsigned short* s_lf = s_p;               // lf_n temp, dead before first P write
  float* s_red = (float*)(smem + OFF_Q);    // load-phase only, dead before first Q write
  unsigned short* s_rpb = (unsigned short*)(smem + OFF_RPB);

  const int tid  = threadIdx.x;
  const int lane = tid & 63;
  const int wv   = tid >> 6;     // wave 0..3
  const int quad = lane >> 4;
  const int l16  = lane & 15;

  // XCD-pair swizzle: consecutive blockIdx round-robins XCDs (MI355X: 8).
  // Remap so XCD x owns the contiguous window range [x*512, x*512+512):
  // wx-adjacent windows (which share every 64B HBM line: window row = 32B)
  // become consecutive dispatches on the SAME XCD -> second half of each
  // line is an L2 hit instead of a second HBM fetch.
  const int g   = blockIdx.x;
  const int wid = ((g & 7) << 9) | (g >> 3);   // 4096 windows, bijective
  const int b   = wid >> 10;
  const int wy  = (wid >> 5) & 31;
  const int wx  = wid & 31;
  const int h0  = wy << 3, w0 = wx << 3;

  const int t_own = tid & 63;          // token owned for load/stats (t = ty*8+tx)
  const int cg    = tid >> 6;          // channel block owner (wave-uniform)
  const int ty    = t_own >> 3, tx = t_own & 7;

  // stage RPB table as bf16 (|rpb| ~ 0.08 -> abs err <= 2e-4, negligible)
  for (int i = tid; i < 225 * NHEAD; i += 256) s_rpb[i] = f2b(rpb[i]);

  // ---- load windows (coalesced 32B row segments) + LN stats in fp32 ----
  // wave cg owns CONTIGUOUS channel blocks: lf [cg*16, +16), hf [cg*48, +48)
  // hfv stays live through the whole kernel: it IS the residual (no re-read).
  float lfv[16], hfv[48];
  float ls = 0.f, l2 = 0.f, hs = 0.f, h2 = 0.f;
  {
    const float* p = ylf + ((size_t)(b * CLF + cg * 16) * IMG + (h0 + ty)) * IMG + (w0 + tx);
#pragma unroll
    for (int k = 0; k < 16; k++) {
      float v = p[(size_t)k * HW];
      lfv[k] = v; ls += v; l2 += v * v;
    }
  }
  {
    const float* p = yhf + ((size_t)(b * CHF + cg * 48) * IMG + (h0 + ty)) * IMG + (w0 + tx);
#pragma unroll
    for (int k = 0; k < 48; k++) {
      float v = p[(size_t)k * HW];
      hfv[k] = v; hs += v; h2 += v * v;
    }
  }
  s_red[0 * 256 + (cg << 6) + t_own] = ls;
  s_red[1 * 256 + (cg << 6) + t_own] = l2;
  s_red[2 * 256 + (cg << 6) + t_own] = hs;
  s_red[3 * 256 + (cg << 6) + t_own] = h2;
  __syncthreads();  // B1
  float su = 0.f, sq = 0.f, hu = 0.f, hq = 0.f;
#pragma unroll
  for (int gg = 0; gg < 4; gg++) {
    su += s_red[0 * 256 + (gg << 6) + t_own];
    sq += s_red[1 * 256 + (gg << 6) + t_own];
    hu += s_red[2 * 256 + (gg << 6) + t_own];
    hq += s_red[3 * 256 + (gg << 6) + t_own];
  }
  const float mu_lf = su * (1.f / 64.f);
  const float rs_lf = rsqrtf(sq * (1.f / 64.f) - mu_lf * mu_lf + 1e-5f);
  const float mu_hf = hu * (1.f / 192.f);
  const float rs_hf = rsqrtf(hq * (1.f / 192.f) - mu_hf * mu_hf + 1e-5f);

  // normalize + packed u64 bf16 stores (4 channels/store)
#pragma unroll
  for (int j = 0; j < 4; j++) {
    uint64_t w = 0;
#pragma unroll
    for (int m = 0; m < 4; m++) {
      int c = cg * 16 + j * 4 + m;
      float v = (lfv[j * 4 + m] - mu_lf) * rs_lf * glf[c] + blf[c];
      w |= (uint64_t)f2b(v) << (16 * m);
    }
    *(uint64_t*)(s_lf + t_own * PP + cg * 16 + j * 4) = w;
  }
#pragma unroll
  for (int j = 0; j < 12; j++) {
    uint64_t w = 0;
#pragma unroll
    for (int m = 0; m < 4; m++) {
      int c = cg * 48 + j * 4 + m;
      float v = (hfv[j * 4 + m] - mu_hf) * rs_hf * ghf[c] + bhf[c];
      w |= (uint64_t)f2b(v) << (16 * m);
    }
    *(uint64_t*)(s_hf + t_own * PHF + cg * 48 + j * 4) = w;
  }
  __syncthreads();  // B2 (also: red-reads before first s_q write; lf-temp before first P write)

  // lf_n A-fragments for this wave's 16 query rows, kept in registers all heads
  bf16x8 alf0 = *(const bf16x8*)(s_lf + (wv * 16 + l16) * PP + quad * 8);
  bf16x8 alf1 = *(const bf16x8*)(s_lf + (wv * 16 + l16) * PP + 32 + quad * 8);

  const unsigned short* wqT = wT;           // [192][64]
  const unsigned short* wkT = wT + 12288;   // [192][192]
  const unsigned short* wvT = wT + 49152;
  const unsigned short* woT = wT + 86016;

  const int rowbase = wv * 16 + quad * 4;   // C-layout row base for this lane

  // O accumulators live across the whole head loop (48 VGPR)
  floatx4 oa[12];
  const floatx4 zero = {0.f, 0.f, 0.f, 0.f};
#pragma unroll
  for (int ct = 0; ct < 12; ct++) oa[ct] = zero;

  for (int h = 0; h < NHEAD; h++) {
    // ---- Q_h = lf_n @ Wq[:, h*32:+32] + bq ----
#pragma unroll
    for (int nt = 0; nt < 2; nt++) {
      const int n = h * 32 + nt * 16 + l16;
      floatx4 acc = {0.f, 0.f, 0.f, 0.f};
      acc = mfma_bf16(alf0, *(const bf16x8*)(wqT + n * 64 + quad * 8), acc);
      acc = mfma_bf16(alf1, *(const bf16x8*)(wqT + n * 64 + 32 + quad * 8), acc);
      const float bqv = bq[n];
#pragma unroll
      for (int r = 0; r < 4; r++)
        s_q[(rowbase + r) * PQK + nt * 16 + l16] = f2b(acc[r] + bqv);
    }
    // ---- K_h ----
#pragma unroll
    for (int nt = 0; nt < 2; nt++) {
      const int n = h * 32 + nt * 16 + l16;
      floatx4 acc = {0.f, 0.f, 0.f, 0.f};
#pragma unroll
      for (int ks = 0; ks < 6; ks++) {
        bf16x8 a  = *(const bf16x8*)(s_hf + (wv * 16 + l16) * PHF + ks * 32 + quad * 8);
        bf16x8 bb = *(const bf16x8*)(wkT + n * 192 + ks * 32 + quad * 8);
        acc = mfma_bf16(a, bb, acc);
      }
      const float bkv = bk[n];
#pragma unroll
      for (int r = 0; r < 4; r++)
        s_k[(rowbase + r) * PQK + nt * 16 + l16] = f2b(acc[r] + bkv);
    }
    // ---- V_h (stored transposed: vt[d][m] so PV B-frags are contiguous) ----
#pragma unroll
    for (int nt = 0; nt < 2; nt++) {
      const int n = h * 32 + nt * 16 + l16;
      floatx4 acc = {0.f, 0.f, 0.f, 0.f};
#pragma unroll
      for (int ks = 0; ks < 6; ks++) {
        bf16x8 a  = *(const bf16x8*)(s_hf + (wv * 16 + l16) * PHF + ks * 32 + quad * 8);
        bf16x8 bb = *(const bf16x8*)(wvT + n * 192 + ks * 32 + quad * 8);
        acc = mfma_bf16(a, bb, acc);
      }
      const float bvv = bv[n];
#pragma unroll
      for (int r = 0; r < 4; r++)
        s_vt[(nt * 16 + l16) * PVT + rowbase + r] = f2b(acc[r] + bvv);
    }
    __syncthreads();  // barrier A: K/V visible to all waves

    // ---- S = Q K^T * scale + rpb bias (wave w owns query rows w*16..+15) ----
    bf16x8 aq = *(const bf16x8*)(s_q + (wv * 16 + l16) * PQK + quad * 8);
    float sv[4][4];
#pragma unroll
    for (int ct = 0; ct < 4; ct++) {
      bf16x8 kb = *(const bf16x8*)(s_k + (ct * 16 + l16) * PQK + quad * 8);
      floatx4 acc = {0.f, 0.f, 0.f, 0.f};
      acc = mfma_bf16(aq, kb, acc);
#pragma unroll
      for (int r = 0; r < 4; r++) {
        int row = rowbase + r, col = ct * 16 + l16;
        int dy = (row >> 3) - (col >> 3) + 7;
        int dx = (row & 7) - (col & 7) + 7;
        sv[ct][r] = acc[r] * 0.17677669529663688f + b2f(s_rpb[(dy * 15 + dx) * NHEAD + h]);
      }
    }
    // ---- softmax over 64 keys: 4 in-lane + xor-shuffle over 16 lanes ----
#pragma unroll
    for (int r = 0; r < 4; r++) {
      float m = fmaxf(fmaxf(sv[0][r], sv[1][r]), fmaxf(sv[2][r], sv[3][r]));
      m = fmaxf(m, __shfl_xor(m, 1));
      m = fmaxf(m, __shfl_xor(m, 2));
      m = fmaxf(m, __shfl_xor(m, 4));
      m = fmaxf(m, __shfl_xor(m, 8));
      const float L2E = 1.4426950408889634f;
      float e0 = exp2f((sv[0][r] - m) * L2E);
      float e1 = exp2f((sv[1][r] - m) * L2E);
      float e2 = exp2f((sv[2][r] - m) * L2E);
      float e3 = exp2f((sv[3][r] - m) * L2E);
      float s = e0 + e1 + e2 + e3;
      s += __shfl_xor(s, 1);
      s += __shfl_xor(s, 2);
      s += __shfl_xor(s, 4);
      s += __shfl_xor(s, 8);
      float inv = 1.f / s;
      sv[0][r] = e0 * inv; sv[1][r] = e1 * inv; sv[2][r] = e2 * inv; sv[3][r] = e3 * inv;
    }
#pragma unroll
    for (int ct = 0; ct < 4; ct++)
#pragma unroll
      for (int r = 0; r < 4; r++)
        s_p[(rowbase + r) * PP + ct * 16 + l16] = f2b(sv[ct][r]);

    // ---- PV: own P rows (same-wave LDS round trip; no barrier needed) ----
    floatx4 pv0 = {0.f, 0.f, 0.f, 0.f}, pv1 = {0.f, 0.f, 0.f, 0.f};
#pragma unroll
    for (int ks = 0; ks < 2; ks++) {
      bf16x8 pa = *(const bf16x8*)(s_p + (wv * 16 + l16) * PP + ks * 32 + quad * 8);
      pv0 = mfma_bf16(pa, *(const bf16x8*)(s_vt + (0 * 16 + l16) * PVT + ks * 32 + quad * 8), pv0);
      pv1 = mfma_bf16(pa, *(const bf16x8*)(s_vt + (1 * 16 + l16) * PVT + ks * 32 + quad * 8), pv1);
    }
    // stage AO_h into s_p cols 0..31 (same-wave DS ops retire in order)
#pragma unroll
    for (int r = 0; r < 4; r++) {
      s_p[(rowbase + r) * PP + l16]      = f2b(pv0[r]);
      s_p[(rowbase + r) * PP + 16 + l16] = f2b(pv1[r]);
    }
    // ---- O += AO_h @ Wo[h*32:(h+1)*32, :]  (register accumulation) ----
    bf16x8 aoh = *(const bf16x8*)(s_p + (wv * 16 + l16) * PP + quad * 8);
#pragma unroll
    for (int ct = 0; ct < 12; ct++) {
      bf16x8 bb = *(const bf16x8*)(woT + (ct * 16 + l16) * 192 + h * 32 + quad * 8);
      oa[ct] = mfma_bf16(aoh, bb, oa[ct]);
    }
    if (h < NHEAD - 1) __syncthreads();  // barrier B: before next head overwrites Q/K/V/P
    // (last head: epilogue writes only this wave's own rows of the dead s_hf region,
    //  and every wave's last s_hf read was before its own barrier A of head 5)
  }

  // ---- epilogue: stage O + bo (own rows, compute mapping) into dead s_hf region ----
  unsigned short* s_res = s_hf;
#pragma unroll
  for (int ct = 0; ct < 12; ct++) {
    const int col = ct * 16 + l16;
    const float bov = bo[col];
#pragma unroll
    for (int r = 0; r < 4; r++)
      s_res[(rowbase + r) * PHF + col] = f2b(oa[ct][r] + bov);
  }
  __syncthreads();  // B4: cross-wave gather follows

  // ---- store with the LOAD mapping: residual comes straight from hfv registers.
  // Scalar 4B stores -> 32B/wave segments; the paired window (same XCD, adjacent
  // dispatch) writes the other half of each 64B line before writeback.
  {
    float* po = out + ((size_t)(b * CHF + cg * 48) * IMG + (h0 + ty)) * IMG + (w0 + tx);
#pragma unroll
    for (int j = 0; j < 12; j++) {
      uint64_t w = *(const uint64_t*)(s_res + t_own * PHF + cg * 48 + j * 4);
#pragma unroll
      for (int m = 0; m < 4; m++) {
        float o = b2f((unsigned short)(w >> (16 * m)));
        po[(size_t)(j * 4 + m) * HW] = o + hfv[j * 4 + m];
      }
    }
  }
}

extern "C" void kernel_launch(void* const* d_in, const int* in_sizes, int n_in,
                              void* d_out, int out_size, void* d_ws, size_t ws_size,
                              hipStream_t stream) {
  const float* ylf = (const float*)d_in[0];
  const float* yhf = (const float*)d_in[1];
  const float* glf = (const float*)d_in[2];
  const float* blf = (const float*)d_in[3];
  const float* ghf = (const float*)d_in[4];
  const float* bhf = (const float*)d_in[5];
  const float* Wq  = (const float*)d_in[6];
  const float* bq  = (const float*)d_in[7];
  const float* Wk  = (const float*)d_in[8];
  const float* bk  = (const float*)d_in[9];
  const float* Wv  = (const float*)d_in[10];
  const float* bv  = (const float*)d_in[11];
  const float* Wo  = (const float*)d_in[12];
  const float* bo  = (const float*)d_in[13];
  const float* rpb = (const float*)d_in[14];
  unsigned short* wT = (unsigned short*)d_ws;  // 122880 bf16 = 245760 B

  wca_prep<<<480, 256, 0, stream>>>(Wq, Wk, Wv, Wo, wT);
  wca_main<<<4096, 256, 0, stream>>>(ylf, yhf, glf, blf, ghf, bhf,
                                     bq, bk, bv, bo, rpb, wT, (float*)d_out);
}